// Round 5
// baseline (396.449 us; speedup 1.0000x reference)
//
#include <hip/hip_runtime.h>
#include <math.h>

#define N_NODES 100000
#define N_EDGES 1600000

#define BUCKETS 8
#define GSPLIT 32
#define BUCKET_NODES (N_NODES / BUCKETS)   // 12500 -> 50 KB LDS
#define NSEG (BUCKETS * GSPLIT)            // 256 segments
#define CAP 8192                           // mean 6250/segment, >24 sigma slack

// ---------------------------------------------------------------------------
// Packed gather tables (each fits a 4MB per-XCD L2):
//   posw[i]   = {pos.xyz, f0}   1.6 MB   featsw[i] = {f1..f8}   3.2 MB
// ---------------------------------------------------------------------------
__global__ __launch_bounds__(256) void pack_kernel(
    const float* __restrict__ pos,
    const float* __restrict__ feats,
    float4* __restrict__ posw,
    float4* __restrict__ featsw)
{
    const int i = blockIdx.x * blockDim.x + threadIdx.x;
    if (i >= N_NODES) return;
    const float* p = pos + 3 * i;
    const float* f = feats + 9 * i;
    posw[i]           = make_float4(p[0], p[1], p[2], f[0]);
    featsw[2 * i + 0] = make_float4(f[1], f[2], f[3], f[4]);
    featsw[2 * i + 1] = make_float4(f[5], f[6], f[7], f[8]);
}

__device__ __forceinline__ float edge_msg(
    const float4 a, const float4 b, const float4 c, const float4 pd,
    const float* __restrict__ sW1, const float* __restrict__ sW2)
{
    const float vx = pd.x - a.x;
    const float vy = pd.y - a.y;
    const float vz = pd.z - a.z;

    const float r   = sqrtf(vx * vx + vy * vy + vz * vz);
    const float inv = 1.0f / (r + 1e-12f);
    const float x = vx * inv, y = vy * inv, z = vz * inv;

    const float s3  = 1.7320508075688772f;
    const float s5  = 2.23606797749979f;
    const float s15 = 3.872983346207417f;
    const float sh1 = s3 * x;
    const float sh2 = s3 * y;
    const float sh3 = s3 * z;
    const float sh4 = s15 * x * z;
    const float sh5 = s15 * x * y;
    const float sh6 = s5 * (y * y - 0.5f * (x * x + z * z));
    const float sh7 = s15 * y * z;
    const float sh8 = 0.5f * s15 * (z * z - x * x);

    // radial basis: q = r*(11/5); active bins k-1, k
    const float q = r * 2.2f;
    const int   k = (int)floorf(q);
    int   b0 = k - 1, b1 = k;
    const float d0 = q - (float)k;
    const float d1 = d0 - 1.0f;
    const float A = 8.43357307f;              // 1.14136 * e^2
    float e0 = 0.0f, e1 = 0.0f;
    if (b0 >= 0 && b0 < 10) {
        const float dd = d0 * d0;
        if (dd < 1.0f) e0 = A * expf(-1.0f / (1.0f - dd));
    }
    if (b1 >= 0 && b1 < 10) {
        const float dd = d1 * d1;
        if (dd < 1.0f) e1 = A * expf(-1.0f / (1.0f - dd));
    }
    b0 = (b0 >= 0 && b0 < 10) ? b0 : 0;
    b1 = (b1 >= 0 && b1 < 10) ? b1 : 0;

    const float* w1r0 = sW1 + b0 * 17;
    const float* w1r1 = sW1 + b1 * 17;
    float acc0 = 0.0f, acc1 = 0.0f, acc2 = 0.0f;
#pragma unroll
    for (int j = 0; j < 16; ++j) {
        const float hj = fmaxf(e0 * w1r0[j] + e1 * w1r1[j], 0.0f);
        acc0 = fmaf(hj, sW2[j * 3 + 0], acc0);
        acc1 = fmaf(hj, sW2[j * 3 + 1], acc1);
        acc2 = fmaf(hj, sW2[j * 3 + 2], acc2);
    }

    const float path_s = a.w;
    const float path_p = (b.x * sh1 + b.y * sh2 + b.z * sh3) * 0.5773502691896258f;
    const float path_d = (b.w * sh4 + c.x * sh5 + c.y * sh6
                        + c.z * sh7 + c.w * sh8) * 0.4472135954999579f;

    const float FINAL = 0.06454972243679028f;  // sqrt(2)/(4*sqrt(3)*sqrt(10))
    return (acc0 * path_s + acc1 * path_p + acc2 * path_d) * FINAL;
}

// ---------------------------------------------------------------------------
// Phase 1 (fused): compute msg AND radix-partition (local_dst, msg) pairs
// into BUCKETS x GSPLIT segments via wave-aggregated counter atomics
// (1 atomic per bucket per wave, 256 counters -> no contention).
// Grid is exactly N_EDGES/256 blocks; no early exit (ballots need all lanes).
// ---------------------------------------------------------------------------
__global__ __launch_bounds__(256) void msg_part_kernel(
    const float4* __restrict__ posw,
    const float4* __restrict__ featsw,
    const float* __restrict__ W1,
    const float* __restrict__ W2,
    const int* __restrict__ edge_src,
    const int* __restrict__ edge_dst,
    int*  __restrict__ counters,          // [NSEG], pre-zeroed
    int2* __restrict__ segs)              // [NSEG][CAP]
{
    __shared__ float sW1[10 * 17];
    __shared__ float sW2[16 * 3];
    const int t = threadIdx.x;
    if (t < 160) sW1[(t >> 4) * 17 + (t & 15)] = W1[t];
    if (t < 48)  sW2[t] = W2[t];
    __syncthreads();

    const int e = blockIdx.x * 256 + t;   // grid exact: 6250*256 == N_EDGES
    const int s = edge_src[e];
    const int d = edge_dst[e];
    const float4 a  = posw[s];
    const float4 bb = featsw[2 * s + 0];
    const float4 cc = featsw[2 * s + 1];
    const float4 p  = posw[d];
    const float m = edge_msg(a, bb, cc, p, sW1, sW2);

    const int g        = blockIdx.x & (GSPLIT - 1);
    const int mybucket = d / BUCKET_NODES;              // 0..7
    const int local    = d - mybucket * BUCKET_NODES;   // 0..12499
    const int lane     = t & 63;

#pragma unroll
    for (int b = 0; b < BUCKETS; ++b) {
        const unsigned long long mask = __ballot(mybucket == b);
        if (mask == 0ull) continue;                      // wave-uniform
        const int leader = __ffsll((unsigned long long)mask) - 1;
        int base = 0;
        if (lane == leader)
            base = atomicAdd(&counters[b * GSPLIT + g], (int)__popcll(mask));
        base = __shfl(base, leader);
        if (mybucket == b) {
            const int rank = (int)__popcll(mask & ((1ull << lane) - 1ull));
            const int slot = base + rank;
            if (slot < CAP)
                segs[(size_t)(b * GSPLIT + g) * CAP + slot] =
                    make_int2(local, __float_as_int(m));
        }
    }
}

// ---------------------------------------------------------------------------
// Phase 2: block = one segment; stream its pairs (all 64 lanes useful),
// dense ds_add_f32 into 50 KB LDS, coalesced slab write.
// ---------------------------------------------------------------------------
__global__ __launch_bounds__(256) void scatter_kernel(
    const int* __restrict__ counters,
    const int2* __restrict__ segs,
    float* __restrict__ slabs)            // [NSEG][BUCKET_NODES]
{
    __shared__ float acc[BUCKET_NODES];
    const int seg = blockIdx.x;
    const int t = threadIdx.x;
    for (int i = t; i < BUCKET_NODES; i += 256) acc[i] = 0.0f;
    __syncthreads();

    int count = counters[seg];
    if (count > CAP) count = CAP;
    const int2* sp = segs + (size_t)seg * CAP;
    for (int i = t; i < count; i += 256) {
        const int2 pr = sp[i];
        atomicAdd(&acc[pr.x], __int_as_float(pr.y));
    }
    __syncthreads();

    float* slab = slabs + (size_t)seg * BUCKET_NODES;
    for (int i = t; i < BUCKET_NODES; i += 256) slab[i] = acc[i];
}

// Phase 3: out[n] = sum over the GSPLIT slabs of n's bucket.
__global__ __launch_bounds__(256) void reduce_kernel(
    const float* __restrict__ slabs, float* __restrict__ out)
{
    const int n = blockIdx.x * blockDim.x + threadIdx.x;
    if (n >= N_NODES) return;
    const int b = n / BUCKET_NODES;
    const int i = n - b * BUCKET_NODES;
    const float* sl = slabs + ((size_t)b * GSPLIT) * BUCKET_NODES + i;
    float sum = 0.0f;
#pragma unroll
    for (int g = 0; g < GSPLIT; ++g) sum += sl[(size_t)g * BUCKET_NODES];
    out[n] = sum;
}

// Fallback (ws too small): direct atomic kernel.
__global__ __launch_bounds__(256) void edge_kernel_direct(
    const float* __restrict__ pos,
    const float* __restrict__ node_feats,
    const float* __restrict__ W1,
    const float* __restrict__ W2,
    const int*   __restrict__ edge_src,
    const int*   __restrict__ edge_dst,
    float* __restrict__ out)
{
    __shared__ float sW1[10 * 17];
    __shared__ float sW2[16 * 3];
    const int t = threadIdx.x;
    if (t < 160) sW1[(t >> 4) * 17 + (t & 15)] = W1[t];
    if (t < 48)  sW2[t] = W2[t];
    __syncthreads();

    const int e = blockIdx.x * blockDim.x + t;
    if (e >= N_EDGES) return;

    const int src = edge_src[e];
    const int dst = edge_dst[e];
    const float* ps = pos + 3 * src;
    const float* pd = pos + 3 * dst;
    const float* xf = node_feats + 9 * src;
    const float4 a = make_float4(ps[0], ps[1], ps[2], xf[0]);
    const float4 b = make_float4(xf[1], xf[2], xf[3], xf[4]);
    const float4 c = make_float4(xf[5], xf[6], xf[7], xf[8]);
    const float4 pdv = make_float4(pd[0], pd[1], pd[2], 0.0f);
    const float m = edge_msg(a, b, c, pdv, sW1, sW2);
    unsafeAtomicAdd(out + dst, m);
}

extern "C" void kernel_launch(void* const* d_in, const int* in_sizes, int n_in,
                              void* d_out, int out_size, void* d_ws, size_t ws_size,
                              hipStream_t stream) {
    const float* pos        = (const float*)d_in[0];
    const float* node_feats = (const float*)d_in[1];
    const float* W1         = (const float*)d_in[2];
    const float* W2         = (const float*)d_in[3];
    const int*   edge_src   = (const int*)d_in[4];
    const int*   edge_dst   = (const int*)d_in[5];
    float* out = (float*)d_out;

    const size_t posw_bytes   = (size_t)N_NODES * sizeof(float4);               // 1.6 MB
    const size_t featsw_bytes = (size_t)N_NODES * 2 * sizeof(float4);           // 3.2 MB
    const size_t cnt_bytes    = (size_t)NSEG * sizeof(int);                     // 1 KB
    const size_t cnt_pad      = 4096;                                           // keep segs aligned
    const size_t seg_bytes    = (size_t)NSEG * CAP * sizeof(int2);              // 16.8 MB
    const size_t slab_bytes   = (size_t)NSEG * BUCKET_NODES * sizeof(float);    // 12.8 MB
    const size_t need = posw_bytes + featsw_bytes + cnt_pad + seg_bytes + slab_bytes;

    if (ws_size >= need) {
        char* w = (char*)d_ws;
        float4* posw   = (float4*)w;  w += posw_bytes;
        float4* featsw = (float4*)w;  w += featsw_bytes;
        int*    cnts   = (int*)w;     w += cnt_pad;
        int2*   segs   = (int2*)w;    w += seg_bytes;
        float*  slabs  = (float*)w;

        hipMemsetAsync(cnts, 0, cnt_bytes, stream);
        pack_kernel<<<(N_NODES + 255) / 256, 256, 0, stream>>>(pos, node_feats, posw, featsw);
        msg_part_kernel<<<N_EDGES / 256, 256, 0, stream>>>(
            posw, featsw, W1, W2, edge_src, edge_dst, cnts, segs);
        scatter_kernel<<<NSEG, 256, 0, stream>>>(cnts, segs, slabs);
        reduce_kernel<<<(N_NODES + 255) / 256, 256, 0, stream>>>(slabs, out);
    } else {
        hipMemsetAsync(out, 0, N_NODES * sizeof(float), stream);
        edge_kernel_direct<<<(N_EDGES + 255) / 256, 256, 0, stream>>>(
            pos, node_feats, W1, W2, edge_src, edge_dst, out);
    }
}

// Round 6
// 129.090 us; speedup vs baseline: 3.0711x; 3.0711x over previous
//
#include <hip/hip_runtime.h>
#include <math.h>

#define N_NODES 100000
#define N_EDGES 1600000

#define BUCKETS 8
#define GSPLIT 32
#define BUCKET_NODES (N_NODES / BUCKETS)   // 12500 -> 50 KB LDS
#define NSEG (BUCKETS * GSPLIT)            // 256 segments
#define CAP 8192                           // mean ~6272/segment, >20 sigma slack
#define CPAD 32                            // ints per counter -> 128 B/line, no line sharing

// ---------------------------------------------------------------------------
// Packed gather tables (each fits a 4MB per-XCD L2):
//   posw[i]   = {pos.xyz, f0}   1.6 MB   featsw[i] = {f1..f8}   3.2 MB
// ---------------------------------------------------------------------------
__global__ __launch_bounds__(256) void pack_kernel(
    const float* __restrict__ pos,
    const float* __restrict__ feats,
    float4* __restrict__ posw,
    float4* __restrict__ featsw)
{
    const int i = blockIdx.x * blockDim.x + threadIdx.x;
    if (i >= N_NODES) return;
    const float* p = pos + 3 * i;
    const float* f = feats + 9 * i;
    posw[i]           = make_float4(p[0], p[1], p[2], f[0]);
    featsw[2 * i + 0] = make_float4(f[1], f[2], f[3], f[4]);
    featsw[2 * i + 1] = make_float4(f[5], f[6], f[7], f[8]);
}

__device__ __forceinline__ float edge_msg(
    const float4 a, const float4 b, const float4 c, const float4 pd,
    const float* __restrict__ sW1, const float* __restrict__ sW2)
{
    const float vx = pd.x - a.x;
    const float vy = pd.y - a.y;
    const float vz = pd.z - a.z;

    const float r   = sqrtf(vx * vx + vy * vy + vz * vz);
    const float inv = 1.0f / (r + 1e-12f);
    const float x = vx * inv, y = vy * inv, z = vz * inv;

    const float s3  = 1.7320508075688772f;
    const float s5  = 2.23606797749979f;
    const float s15 = 3.872983346207417f;
    const float sh1 = s3 * x;
    const float sh2 = s3 * y;
    const float sh3 = s3 * z;
    const float sh4 = s15 * x * z;
    const float sh5 = s15 * x * y;
    const float sh6 = s5 * (y * y - 0.5f * (x * x + z * z));
    const float sh7 = s15 * y * z;
    const float sh8 = 0.5f * s15 * (z * z - x * x);

    // radial basis: q = r*(11/5); active bins k-1, k
    const float q = r * 2.2f;
    const int   k = (int)floorf(q);
    int   b0 = k - 1, b1 = k;
    const float d0 = q - (float)k;
    const float d1 = d0 - 1.0f;
    const float A = 8.43357307f;              // 1.14136 * e^2
    float e0 = 0.0f, e1 = 0.0f;
    if (b0 >= 0 && b0 < 10) {
        const float dd = d0 * d0;
        if (dd < 1.0f) e0 = A * expf(-1.0f / (1.0f - dd));
    }
    if (b1 >= 0 && b1 < 10) {
        const float dd = d1 * d1;
        if (dd < 1.0f) e1 = A * expf(-1.0f / (1.0f - dd));
    }
    b0 = (b0 >= 0 && b0 < 10) ? b0 : 0;
    b1 = (b1 >= 0 && b1 < 10) ? b1 : 0;

    const float* w1r0 = sW1 + b0 * 17;
    const float* w1r1 = sW1 + b1 * 17;
    float acc0 = 0.0f, acc1 = 0.0f, acc2 = 0.0f;
#pragma unroll
    for (int j = 0; j < 16; ++j) {
        const float hj = fmaxf(e0 * w1r0[j] + e1 * w1r1[j], 0.0f);
        acc0 = fmaf(hj, sW2[j * 3 + 0], acc0);
        acc1 = fmaf(hj, sW2[j * 3 + 1], acc1);
        acc2 = fmaf(hj, sW2[j * 3 + 2], acc2);
    }

    const float path_s = a.w;
    const float path_p = (b.x * sh1 + b.y * sh2 + b.z * sh3) * 0.5773502691896258f;
    const float path_d = (b.w * sh4 + c.x * sh5 + c.y * sh6
                        + c.z * sh7 + c.w * sh8) * 0.4472135954999579f;

    const float FINAL = 0.06454972243679028f;  // sqrt(2)/(4*sqrt(3)*sqrt(10))
    return (acc0 * path_s + acc1 * path_p + acc2 * path_d) * FINAL;
}

// ---------------------------------------------------------------------------
// Phase 1 (fused): compute msg AND radix-partition (local_dst, msg) into
// BUCKETS x GSPLIT segments. Block-aggregated: per-thread rank from an LDS
// atomic, then only 8 global atomics per block onto 128B-padded counters
// (256 independent lines -> no line serialization, unlike round 5).
// ---------------------------------------------------------------------------
__global__ __launch_bounds__(256) void msg_part_kernel(
    const float4* __restrict__ posw,
    const float4* __restrict__ featsw,
    const float* __restrict__ W1,
    const float* __restrict__ W2,
    const int* __restrict__ edge_src,
    const int* __restrict__ edge_dst,
    int*  __restrict__ counters,          // [NSEG*CPAD], pre-zeroed
    int2* __restrict__ segs)              // [NSEG][CAP]
{
    __shared__ float sW1[10 * 17];
    __shared__ float sW2[16 * 3];
    __shared__ int cnt[BUCKETS];
    __shared__ int basesm[BUCKETS];
    const int t = threadIdx.x;
    if (t < 160) sW1[(t >> 4) * 17 + (t & 15)] = W1[t];
    if (t < 48)  sW2[t] = W2[t];
    if (t < BUCKETS) cnt[t] = 0;
    __syncthreads();

    const int e = blockIdx.x * 256 + t;   // grid exact: 6250*256 == N_EDGES
    const int s = edge_src[e];
    const int d = edge_dst[e];
    const float4 a  = posw[s];
    const float4 bb = featsw[2 * s + 0];
    const float4 cc = featsw[2 * s + 1];
    const float4 p  = posw[d];
    const float m = edge_msg(a, bb, cc, p, sW1, sW2);

    const int mybucket = d / BUCKET_NODES;              // 0..7
    const int local    = d - mybucket * BUCKET_NODES;   // 0..12499
    const int rank = atomicAdd(&cnt[mybucket], 1);      // LDS atomic
    __syncthreads();

    const int g = blockIdx.x & (GSPLIT - 1);
    if (t < BUCKETS)
        basesm[t] = atomicAdd(&counters[(t * GSPLIT + g) * CPAD], cnt[t]);
    __syncthreads();

    const int slot = basesm[mybucket] + rank;
    if (slot < CAP)
        segs[(size_t)(mybucket * GSPLIT + g) * CAP + slot] =
            make_int2(local, __float_as_int(m));
}

// ---------------------------------------------------------------------------
// Phase 2: block = one segment; stream its pairs (all 64 lanes useful),
// dense ds_add_f32 into 50 KB LDS, coalesced slab write.
// ---------------------------------------------------------------------------
__global__ __launch_bounds__(256) void scatter_kernel(
    const int* __restrict__ counters,
    const int2* __restrict__ segs,
    float* __restrict__ slabs)            // [NSEG][BUCKET_NODES]
{
    __shared__ float acc[BUCKET_NODES];
    const int seg = blockIdx.x;
    const int t = threadIdx.x;
    for (int i = t; i < BUCKET_NODES; i += 256) acc[i] = 0.0f;
    __syncthreads();

    int count = counters[seg * CPAD];
    if (count > CAP) count = CAP;
    const int2* sp = segs + (size_t)seg * CAP;
    for (int i = t; i < count; i += 256) {
        const int2 pr = sp[i];
        atomicAdd(&acc[pr.x], __int_as_float(pr.y));
    }
    __syncthreads();

    float* slab = slabs + (size_t)seg * BUCKET_NODES;
    for (int i = t; i < BUCKET_NODES; i += 256) slab[i] = acc[i];
}

// Phase 3: out[n] = sum over the GSPLIT slabs of n's bucket.
__global__ __launch_bounds__(256) void reduce_kernel(
    const float* __restrict__ slabs, float* __restrict__ out)
{
    const int n = blockIdx.x * blockDim.x + threadIdx.x;
    if (n >= N_NODES) return;
    const int b = n / BUCKET_NODES;
    const int i = n - b * BUCKET_NODES;
    const float* sl = slabs + ((size_t)b * GSPLIT) * BUCKET_NODES + i;
    float sum = 0.0f;
#pragma unroll
    for (int g = 0; g < GSPLIT; ++g) sum += sl[(size_t)g * BUCKET_NODES];
    out[n] = sum;
}

// Fallback (ws too small): direct atomic kernel (round-3 87us path).
__global__ __launch_bounds__(256) void edge_kernel_direct(
    const float* __restrict__ pos,
    const float* __restrict__ node_feats,
    const float* __restrict__ W1,
    const float* __restrict__ W2,
    const int*   __restrict__ edge_src,
    const int*   __restrict__ edge_dst,
    float* __restrict__ out)
{
    __shared__ float sW1[10 * 17];
    __shared__ float sW2[16 * 3];
    const int t = threadIdx.x;
    if (t < 160) sW1[(t >> 4) * 17 + (t & 15)] = W1[t];
    if (t < 48)  sW2[t] = W2[t];
    __syncthreads();

    const int e = blockIdx.x * blockDim.x + t;
    if (e >= N_EDGES) return;

    const int src = edge_src[e];
    const int dst = edge_dst[e];
    const float* ps = pos + 3 * src;
    const float* pd = pos + 3 * dst;
    const float* xf = node_feats + 9 * src;
    const float4 a = make_float4(ps[0], ps[1], ps[2], xf[0]);
    const float4 b = make_float4(xf[1], xf[2], xf[3], xf[4]);
    const float4 c = make_float4(xf[5], xf[6], xf[7], xf[8]);
    const float4 pdv = make_float4(pd[0], pd[1], pd[2], 0.0f);
    const float m = edge_msg(a, b, c, pdv, sW1, sW2);
    unsafeAtomicAdd(out + dst, m);
}

extern "C" void kernel_launch(void* const* d_in, const int* in_sizes, int n_in,
                              void* d_out, int out_size, void* d_ws, size_t ws_size,
                              hipStream_t stream) {
    const float* pos        = (const float*)d_in[0];
    const float* node_feats = (const float*)d_in[1];
    const float* W1         = (const float*)d_in[2];
    const float* W2         = (const float*)d_in[3];
    const int*   edge_src   = (const int*)d_in[4];
    const int*   edge_dst   = (const int*)d_in[5];
    float* out = (float*)d_out;

    const size_t posw_bytes   = (size_t)N_NODES * sizeof(float4);               // 1.6 MB
    const size_t featsw_bytes = (size_t)N_NODES * 2 * sizeof(float4);           // 3.2 MB
    const size_t cnt_bytes    = (size_t)NSEG * CPAD * sizeof(int);              // 32 KB
    const size_t seg_bytes    = (size_t)NSEG * CAP * sizeof(int2);              // 16.8 MB
    const size_t slab_bytes   = (size_t)NSEG * BUCKET_NODES * sizeof(float);    // 12.8 MB
    const size_t need = posw_bytes + featsw_bytes + cnt_bytes + seg_bytes + slab_bytes;

    if (ws_size >= need) {
        char* w = (char*)d_ws;
        float4* posw   = (float4*)w;  w += posw_bytes;
        float4* featsw = (float4*)w;  w += featsw_bytes;
        int*    cnts   = (int*)w;     w += cnt_bytes;
        int2*   segs   = (int2*)w;    w += seg_bytes;
        float*  slabs  = (float*)w;

        hipMemsetAsync(cnts, 0, cnt_bytes, stream);
        pack_kernel<<<(N_NODES + 255) / 256, 256, 0, stream>>>(pos, node_feats, posw, featsw);
        msg_part_kernel<<<N_EDGES / 256, 256, 0, stream>>>(
            posw, featsw, W1, W2, edge_src, edge_dst, cnts, segs);
        scatter_kernel<<<NSEG, 256, 0, stream>>>(cnts, segs, slabs);
        reduce_kernel<<<(N_NODES + 255) / 256, 256, 0, stream>>>(slabs, out);
    } else {
        hipMemsetAsync(out, 0, N_NODES * sizeof(float), stream);
        edge_kernel_direct<<<(N_EDGES + 255) / 256, 256, 0, stream>>>(
            pos, node_feats, W1, W2, edge_src, edge_dst, out);
    }
}

// Round 7
// 122.227 us; speedup vs baseline: 3.2435x; 1.0561x over previous
//
#include <hip/hip_runtime.h>
#include <math.h>

#define N_NODES 100000
#define N_EDGES 1600000

#define BUCKETS 8
#define GSPLIT 32
#define BUCKET_NODES (N_NODES / BUCKETS)   // 12500 -> 50 KB LDS
#define NSEG (BUCKETS * GSPLIT)            // 256 segments
#define CAP 8192                           // mean ~6250/segment, >20 sigma slack
#define CPAD 32                            // ints per counter -> 128 B line each

typedef _Float16 half8 __attribute__((ext_vector_type(8)));
typedef _Float16 half4 __attribute__((ext_vector_type(4)));

// ---------------------------------------------------------------------------
// fp16 packed gather tables (together 4.0 MB -> fit ONE per-XCD L2):
//   srcw[i] = 32 B: {pos.xyz, f0..f8, pad4}  (3.2 MB; one line per node)
//   posh[i] =  8 B: {pos.xyz, pad}           (0.8 MB)
// Also zeroes the 32KB padded counters (block 0) - saves a memset dispatch.
// ---------------------------------------------------------------------------
__global__ __launch_bounds__(256) void pack_kernel(
    const float* __restrict__ pos,
    const float* __restrict__ feats,
    half8* __restrict__ srcw,             // [N_NODES*2]
    half4* __restrict__ posh,             // [N_NODES]
    int*   __restrict__ counters)         // [NSEG*CPAD]
{
    const int i = blockIdx.x * blockDim.x + threadIdx.x;
    if (blockIdx.x == 0) {
        for (int c = threadIdx.x; c < NSEG * CPAD; c += 256) counters[c] = 0;
    }
    if (i >= N_NODES) return;
    const float* p = pos + 3 * i;
    const float* f = feats + 9 * i;
    half8 a, b;
    a[0] = (_Float16)p[0]; a[1] = (_Float16)p[1]; a[2] = (_Float16)p[2];
    a[3] = (_Float16)f[0]; a[4] = (_Float16)f[1]; a[5] = (_Float16)f[2];
    a[6] = (_Float16)f[3]; a[7] = (_Float16)f[4];
    b[0] = (_Float16)f[5]; b[1] = (_Float16)f[6]; b[2] = (_Float16)f[7];
    b[3] = (_Float16)f[8]; b[4] = (_Float16)0; b[5] = (_Float16)0;
    b[6] = (_Float16)0;    b[7] = (_Float16)0;
    srcw[2 * i + 0] = a;
    srcw[2 * i + 1] = b;
    half4 q;
    q[0] = (_Float16)p[0]; q[1] = (_Float16)p[1]; q[2] = (_Float16)p[2];
    q[3] = (_Float16)0;
    posh[i] = q;
}

__device__ __forceinline__ float edge_msg_h(
    const half8 ra, const half8 rb, const half4 pd,
    const float* __restrict__ sW1, const float* __restrict__ sW2)
{
    const float vx = (float)pd[0] - (float)ra[0];
    const float vy = (float)pd[1] - (float)ra[1];
    const float vz = (float)pd[2] - (float)ra[2];

    const float r   = sqrtf(vx * vx + vy * vy + vz * vz);
    const float inv = 1.0f / (r + 1e-12f);
    const float x = vx * inv, y = vy * inv, z = vz * inv;

    const float s3  = 1.7320508075688772f;
    const float s5  = 2.23606797749979f;
    const float s15 = 3.872983346207417f;
    const float sh1 = s3 * x;
    const float sh2 = s3 * y;
    const float sh3 = s3 * z;
    const float sh4 = s15 * x * z;
    const float sh5 = s15 * x * y;
    const float sh6 = s5 * (y * y - 0.5f * (x * x + z * z));
    const float sh7 = s15 * y * z;
    const float sh8 = 0.5f * s15 * (z * z - x * x);

    // radial basis: q = r*(11/5); active bins k-1, k
    const float q = r * 2.2f;
    const int   k = (int)floorf(q);
    int   b0 = k - 1, b1 = k;
    const float d0 = q - (float)k;
    const float d1 = d0 - 1.0f;
    const float A = 8.43357307f;              // 1.14136 * e^2
    float e0 = 0.0f, e1 = 0.0f;
    if (b0 >= 0 && b0 < 10) {
        const float dd = d0 * d0;
        if (dd < 1.0f) e0 = A * expf(-1.0f / (1.0f - dd));
    }
    if (b1 >= 0 && b1 < 10) {
        const float dd = d1 * d1;
        if (dd < 1.0f) e1 = A * expf(-1.0f / (1.0f - dd));
    }
    b0 = (b0 >= 0 && b0 < 10) ? b0 : 0;
    b1 = (b1 >= 0 && b1 < 10) ? b1 : 0;

    const float* w1r0 = sW1 + b0 * 17;
    const float* w1r1 = sW1 + b1 * 17;
    float acc0 = 0.0f, acc1 = 0.0f, acc2 = 0.0f;
#pragma unroll
    for (int j = 0; j < 16; ++j) {
        const float hj = fmaxf(e0 * w1r0[j] + e1 * w1r1[j], 0.0f);
        acc0 = fmaf(hj, sW2[j * 3 + 0], acc0);
        acc1 = fmaf(hj, sW2[j * 3 + 1], acc1);
        acc2 = fmaf(hj, sW2[j * 3 + 2], acc2);
    }

    const float path_s = (float)ra[3];
    const float path_p = ((float)ra[4] * sh1 + (float)ra[5] * sh2
                        + (float)ra[6] * sh3) * 0.5773502691896258f;
    const float path_d = ((float)ra[7] * sh4 + (float)rb[0] * sh5
                        + (float)rb[1] * sh6 + (float)rb[2] * sh7
                        + (float)rb[3] * sh8) * 0.4472135954999579f;

    const float FINAL = 0.06454972243679028f;  // sqrt(2)/(4*sqrt(3)*sqrt(10))
    return (acc0 * path_s + acc1 * path_p + acc2 * path_d) * FINAL;
}

// ---------------------------------------------------------------------------
// Phase 1 (fused): msg + radix-partition into BUCKETS x GSPLIT segments.
// Block-aggregated: LDS-atomic rank, 8 global atomics/block onto 128B-padded
// counters (R6 structure - proven). Gathers: 2 cache lines per edge.
// ---------------------------------------------------------------------------
__global__ __launch_bounds__(256) void msg_part_kernel(
    const half8* __restrict__ srcw,
    const half4* __restrict__ posh,
    const float* __restrict__ W1,
    const float* __restrict__ W2,
    const int* __restrict__ edge_src,
    const int* __restrict__ edge_dst,
    int*  __restrict__ counters,          // [NSEG*CPAD], zeroed by pack_kernel
    int2* __restrict__ segs)              // [NSEG][CAP]
{
    __shared__ float sW1[10 * 17];
    __shared__ float sW2[16 * 3];
    __shared__ int cnt[BUCKETS];
    __shared__ int basesm[BUCKETS];
    const int t = threadIdx.x;
    if (t < 160) sW1[(t >> 4) * 17 + (t & 15)] = W1[t];
    if (t < 48)  sW2[t] = W2[t];
    if (t < BUCKETS) cnt[t] = 0;
    __syncthreads();

    const int e = blockIdx.x * 256 + t;   // grid exact: 6250*256 == N_EDGES
    const int s = edge_src[e];
    const int d = edge_dst[e];
    const half8 ra = srcw[2 * s + 0];     // same 64B line as rb
    const half8 rb = srcw[2 * s + 1];
    const half4 pd = posh[d];
    const float m = edge_msg_h(ra, rb, pd, sW1, sW2);

    const int mybucket = d / BUCKET_NODES;              // 0..7
    const int local    = d - mybucket * BUCKET_NODES;   // 0..12499
    const int rank = atomicAdd(&cnt[mybucket], 1);      // LDS atomic
    __syncthreads();

    const int g = blockIdx.x & (GSPLIT - 1);
    if (t < BUCKETS)
        basesm[t] = atomicAdd(&counters[(t * GSPLIT + g) * CPAD], cnt[t]);
    __syncthreads();

    const int slot = basesm[mybucket] + rank;
    if (slot < CAP)
        segs[(size_t)(mybucket * GSPLIT + g) * CAP + slot] =
            make_int2(local, __float_as_int(m));
}

// ---------------------------------------------------------------------------
// Phase 2: block = one segment; stream its pairs (all lanes useful),
// dense ds_add_f32 into 50 KB LDS, coalesced slab write.
// ---------------------------------------------------------------------------
__global__ __launch_bounds__(256) void scatter_kernel(
    const int* __restrict__ counters,
    const int2* __restrict__ segs,
    float* __restrict__ slabs)            // [NSEG][BUCKET_NODES]
{
    __shared__ float acc[BUCKET_NODES];
    const int seg = blockIdx.x;
    const int t = threadIdx.x;
    for (int i = t; i < BUCKET_NODES; i += 256) acc[i] = 0.0f;
    __syncthreads();

    int count = counters[seg * CPAD];
    if (count > CAP) count = CAP;
    const int2* sp = segs + (size_t)seg * CAP;
    for (int i = t; i < count; i += 256) {
        const int2 pr = sp[i];
        atomicAdd(&acc[pr.x], __int_as_float(pr.y));
    }
    __syncthreads();

    float* slab = slabs + (size_t)seg * BUCKET_NODES;
    for (int i = t; i < BUCKET_NODES; i += 256) slab[i] = acc[i];
}

// Phase 3: out[n] = sum over the GSPLIT slabs of n's bucket.
__global__ __launch_bounds__(256) void reduce_kernel(
    const float* __restrict__ slabs, float* __restrict__ out)
{
    const int n = blockIdx.x * blockDim.x + threadIdx.x;
    if (n >= N_NODES) return;
    const int b = n / BUCKET_NODES;
    const int i = n - b * BUCKET_NODES;
    const float* sl = slabs + ((size_t)b * GSPLIT) * BUCKET_NODES + i;
    float sum = 0.0f;
#pragma unroll
    for (int g = 0; g < GSPLIT; ++g) sum += sl[(size_t)g * BUCKET_NODES];
    out[n] = sum;
}

// Fallback (ws too small): direct atomic kernel (round-3 87us path).
__global__ __launch_bounds__(256) void edge_kernel_direct(
    const float* __restrict__ pos,
    const float* __restrict__ node_feats,
    const float* __restrict__ W1,
    const float* __restrict__ W2,
    const int*   __restrict__ edge_src,
    const int*   __restrict__ edge_dst,
    float* __restrict__ out)
{
    __shared__ float sW1[10 * 17];
    __shared__ float sW2[16 * 3];
    const int t = threadIdx.x;
    if (t < 160) sW1[(t >> 4) * 17 + (t & 15)] = W1[t];
    if (t < 48)  sW2[t] = W2[t];
    __syncthreads();

    const int e = blockIdx.x * blockDim.x + t;
    if (e >= N_EDGES) return;

    const int src = edge_src[e];
    const int dst = edge_dst[e];
    const float* ps = pos + 3 * src;
    const float* pdp = pos + 3 * dst;
    const float* xf = node_feats + 9 * src;
    half8 ra, rb; half4 pd;
    ra[0] = (_Float16)ps[0]; ra[1] = (_Float16)ps[1]; ra[2] = (_Float16)ps[2];
    ra[3] = (_Float16)xf[0]; ra[4] = (_Float16)xf[1]; ra[5] = (_Float16)xf[2];
    ra[6] = (_Float16)xf[3]; ra[7] = (_Float16)xf[4];
    rb[0] = (_Float16)xf[5]; rb[1] = (_Float16)xf[6]; rb[2] = (_Float16)xf[7];
    rb[3] = (_Float16)xf[8]; rb[4] = rb[5] = rb[6] = rb[7] = (_Float16)0;
    pd[0] = (_Float16)pdp[0]; pd[1] = (_Float16)pdp[1]; pd[2] = (_Float16)pdp[2];
    pd[3] = (_Float16)0;
    const float m = edge_msg_h(ra, rb, pd, sW1, sW2);
    unsafeAtomicAdd(out + dst, m);
}

extern "C" void kernel_launch(void* const* d_in, const int* in_sizes, int n_in,
                              void* d_out, int out_size, void* d_ws, size_t ws_size,
                              hipStream_t stream) {
    const float* pos        = (const float*)d_in[0];
    const float* node_feats = (const float*)d_in[1];
    const float* W1         = (const float*)d_in[2];
    const float* W2         = (const float*)d_in[3];
    const int*   edge_src   = (const int*)d_in[4];
    const int*   edge_dst   = (const int*)d_in[5];
    float* out = (float*)d_out;

    const size_t srcw_bytes = (size_t)N_NODES * 2 * sizeof(half8);            // 3.2 MB
    const size_t posh_bytes = (size_t)N_NODES * sizeof(half4);                // 0.8 MB
    const size_t cnt_bytes  = (size_t)NSEG * CPAD * sizeof(int);              // 32 KB
    const size_t seg_bytes  = (size_t)NSEG * CAP * sizeof(int2);              // 16.8 MB
    const size_t slab_bytes = (size_t)NSEG * BUCKET_NODES * sizeof(float);    // 12.8 MB
    const size_t need = srcw_bytes + posh_bytes + cnt_bytes + seg_bytes + slab_bytes;

    if (ws_size >= need) {
        char* w = (char*)d_ws;
        half8* srcw  = (half8*)w;  w += srcw_bytes;
        half4* posh  = (half4*)w;  w += posh_bytes;
        int*   cnts  = (int*)w;    w += cnt_bytes;
        int2*  segs  = (int2*)w;   w += seg_bytes;
        float* slabs = (float*)w;

        pack_kernel<<<(N_NODES + 255) / 256, 256, 0, stream>>>(
            pos, node_feats, srcw, posh, cnts);
        msg_part_kernel<<<N_EDGES / 256, 256, 0, stream>>>(
            srcw, posh, W1, W2, edge_src, edge_dst, cnts, segs);
        scatter_kernel<<<NSEG, 256, 0, stream>>>(cnts, segs, slabs);
        reduce_kernel<<<(N_NODES + 255) / 256, 256, 0, stream>>>(slabs, out);
    } else {
        hipMemsetAsync(out, 0, N_NODES * sizeof(float), stream);
        edge_kernel_direct<<<(N_EDGES + 255) / 256, 256, 0, stream>>>(
            pos, node_feats, W1, W2, edge_src, edge_dst, out);
    }
}